// Round 3
// baseline (45772.122 us; speedup 1.0000x reference)
//
#include <hip/hip_runtime.h>
#include <math.h>

// LSTM: B=64, T=784, I=1, H=600.
// Quad decomposition: 256 WGs = 64 batches x 4 quads; one CU per WG.
// Each WG: one batch, 150 cells (600 gate-rows), W_hh slice in REGISTERS.
#define BB 64
#define TT 784
#define HH 600
#define KP 608            // padded K = 8 * 76
#define NWG 256
#define BLOCK 960         // 15 waves; wave owns 10 cells (all 4 gates)
#define CELLS 150
#define LDS_BYTES (84*1024)   // forces 1 WG/CU (2x84 > 160 KiB)

__device__ __forceinline__ float dot4acc(float4 a, float4 b, float acc) {
    acc = fmaf(a.x, b.x, acc);
    acc = fmaf(a.y, b.y, acc);
    acc = fmaf(a.z, b.z, acc);
    acc = fmaf(a.w, b.w, acc);
    return acc;
}

// cache-bypassing 8B load (IF$ coherence point)
__device__ __forceinline__ float2 ldg2_bypass(const float2* g) {
    float2 v;
    asm volatile("global_load_dwordx2 %0, %1, off sc0 sc1\n\t"
                 "s_waitcnt vmcnt(0)"
                 : "=&v"(v) : "v"(g) : "memory");
    return v;
}

__device__ __forceinline__ void stg_bypass(float* p, float v) {
    asm volatile("global_store_dword %0, %1, off sc0 sc1"
                 :: "v"(p), "v"(v) : "memory");
}

__device__ __forceinline__ float sigm_f(float v) {
    return 1.f / (1.f + __expf(-v));
}
__device__ __forceinline__ float tanh_f(float v) {
    return 1.f - 2.f / (__expf(2.f * v) + 1.f);
}

extern "C" __global__ void __launch_bounds__(BLOCK, 1)
lstm_main(const float* __restrict__ x, const float* __restrict__ hs0,
          const float* __restrict__ cs0, const float* __restrict__ W_ih,
          const float* __restrict__ W_hh, const float* __restrict__ b_ih,
          const float* __restrict__ b_hh, float* __restrict__ hbuf,
          unsigned int* __restrict__ flags)
{
    extern __shared__ float lds[];
    float* h_lds = lds;            // [608] this batch's h, indexed by global k
    float* g_lds = lds + KP;       // [4][152] gate gather array

    const int wg   = blockIdx.x;
    const int b    = wg >> 2;      // batch
    const int q    = wg & 3;       // quadrant
    const int tid  = threadIdx.x;
    const int wv   = tid >> 6;     // wave 0..14
    const int lane = tid & 63;
    const int kg   = lane >> 3;    // k-group 0..7 (76 k each)
    const int rg   = lane & 7;     // row-group 0..7
    const int c0   = q * CELLS;    // global cell base for this WG
    const int g    = rg >> 1;      // gate owned by this lane (i,f,g,o = 0..3)
    const int clb  = (rg & 1) * 5; // cell sub-offset within wave

    // ---- one-time: W_hh slice into registers: 5 rows x 19 float4 ----
    float4 Wr[5][19];
    #pragma unroll
    for (int r = 0; r < 5; ++r) {
        const int cell = c0 + 10 * wv + clb + r;
        const float* wrow = W_hh + (size_t)(g * HH + cell) * HH + kg * 76;
        #pragma unroll
        for (int j = 0; j < 19; ++j) {
            if (j < 17 || kg < 7)
                Wr[r][j] = *(const float4*)(wrow + 4 * j);
            else
                Wr[r][j] = make_float4(0.f, 0.f, 0.f, 0.f);   // k >= 600 pad
        }
    }

    // ---- pointwise-lane constants (tid < 150 owns cell c0+tid) ----
    float wihv[4], biasv[4], cst = 0.f;
    if (tid < CELLS) {
        const int cell = c0 + tid;
        #pragma unroll
        for (int gg = 0; gg < 4; ++gg) {
            const int grow = gg * HH + cell;
            wihv[gg]  = W_ih[grow];
            biasv[gg] = b_ih[grow] + b_hh[grow];
        }
        cst = cs0[(size_t)b * HH + cell];
    }

    // ---- stage-lane constants (tid < 225: 3 peers x 75 float2) ----
    int pwg = 0, srcoff = 0, dstoff = 0;
    if (tid < 225) {
        const int p  = tid / 75;            // peer ordinal 0..2
        const int tl = tid - p * 75;
        const int qp = p + (p >= q);        // peer quadrant
        pwg    = (b << 2) | qp;
        srcoff = qp * CELLS + 2 * tl;       // within this batch's h row
        dstoff = qp * CELLS + 2 * tl;
    }

    // ---- init LDS h from hs0, zero the pad ----
    if (tid < CELLS) {
        float4 hv = *(const float4*)(hs0 + (size_t)b * HH + 4 * tid);
        *(float4*)&h_lds[4 * tid] = hv;
    }
    if (tid >= CELLS && tid < CELLS + 8)
        h_lds[HH + (tid - CELLS)] = 0.f;
    __syncthreads();

    unsigned int* myflag = &flags[wg * 64];

    for (int t = 0; t < TT; ++t) {
        // early x broadcast load (read-only, cached)
        float xv = 0.f;
        if (tid < CELLS) xv = x[(size_t)b * TT + t];

        if (t > 0) {
            // fused wait + stage: each of 225 threads polls its peer's flag,
            // then immediately pulls its 8B of that peer's h slice via IF$.
            if (tid < 225) {
                const unsigned int* f = &flags[pwg * 64];
                while (__hip_atomic_load(f, __ATOMIC_RELAXED,
                                         __HIP_MEMORY_SCOPE_AGENT) < (unsigned)t) {}
                const float* hsrc = hbuf + (size_t)(t & 1) * BB * HH
                                         + (size_t)b * HH + srcoff;
                float2 v = ldg2_bypass((const float2*)hsrc);
                *(float2*)&h_lds[dstoff] = v;
            }
            __syncthreads();
        }

        // ---- GEMV: acc[r] = sum over this lane's 76-k slice ----
        float acc[5] = {0.f, 0.f, 0.f, 0.f, 0.f};
        const float4* h4 = (const float4*)h_lds + kg * 19;
        #pragma unroll
        for (int j = 0; j < 19; ++j) {
            float4 hv = h4[j];                 // 8-way broadcast, conflict-free
            #pragma unroll
            for (int r = 0; r < 5; ++r)
                acc[r] = dot4acc(Wr[r][j], hv, acc[r]);
        }

        // ---- butterfly reduce across the 8 kg lanes (lane bits 3..5) ----
        #pragma unroll
        for (int r = 0; r < 5; ++r) {
            float v = acc[r];
            v += __shfl_xor(v, 8);
            v += __shfl_xor(v, 16);
            v += __shfl_xor(v, 32);
            acc[r] = v;
        }

        // ---- gather gates to LDS (one lane per row-group) ----
        if (kg == 0) {
            #pragma unroll
            for (int r = 0; r < 5; ++r)
                g_lds[g * 152 + 10 * wv + clb + r] = acc[r];
        }
        __syncthreads();

        // ---- pointwise LSTM cell update ----
        float* hdst = hbuf + (size_t)((t + 1) & 1) * BB * HH;
        if (tid < CELLS) {
            float gi = g_lds[0 * 152 + tid] + xv * wihv[0] + biasv[0];
            float gf = g_lds[1 * 152 + tid] + xv * wihv[1] + biasv[1];
            float gg = g_lds[2 * 152 + tid] + xv * wihv[2] + biasv[2];
            float go = g_lds[3 * 152 + tid] + xv * wihv[3] + biasv[3];
            float cn = sigm_f(gf) * cst + sigm_f(gi) * tanh_f(gg);
            cst = cn;
            float hv = sigm_f(go) * tanh_f(cn);
            h_lds[c0 + tid] = hv;                       // own slice for next step
            stg_bypass(&hdst[(size_t)b * HH + c0 + tid], hv);  // for peers
        }
        asm volatile("s_waitcnt vmcnt(0)" ::: "memory"); // drain bypass stores
        __syncthreads();
        if (tid == 0)
            __hip_atomic_store(myflag, (unsigned)(t + 1), __ATOMIC_RELAXED,
                               __HIP_MEMORY_SCOPE_AGENT);
    }
}

// final projection: out[b,o] = h_T[b,:] @ W_out[o,:] + b_out[o]
extern "C" __global__ void lstm_out(const float* __restrict__ hbuf0,
                                    const float* __restrict__ W_out,
                                    const float* __restrict__ b_out,
                                    float* __restrict__ out)
{
    int b = blockIdx.x;
    int lane = threadIdx.x;
    float acc[10] = {};
    for (int k = lane; k < HH; k += 64) {
        float hv = hbuf0[(size_t)b * HH + k];
        #pragma unroll
        for (int o = 0; o < 10; ++o)
            acc[o] += hv * W_out[(size_t)o * HH + k];
    }
    #pragma unroll
    for (int o = 0; o < 10; ++o) {
        float v = acc[o];
        for (int off = 32; off > 0; off >>= 1) v += __shfl_down(v, off);
        if (lane == 0) out[b * 10 + o] = v + b_out[o];
    }
}

extern "C" void kernel_launch(void* const* d_in, const int* in_sizes, int n_in,
                              void* d_out, int out_size, void* d_ws, size_t ws_size,
                              hipStream_t stream)
{
    const float* x     = (const float*)d_in[0];
    const float* hs0   = (const float*)d_in[1];
    const float* cs0   = (const float*)d_in[2];
    const float* W_ih  = (const float*)d_in[3];
    const float* W_hh  = (const float*)d_in[4];
    const float* b_ih  = (const float*)d_in[5];
    const float* b_hh  = (const float*)d_in[6];
    const float* W_out = (const float*)d_in[7];
    const float* b_out = (const float*)d_in[8];
    float* out = (float*)d_out;

    // workspace: hbuf[2][64][600] f32, then flags[256] spaced 256 B apart
    float* hbuf = (float*)d_ws;
    unsigned int* flags = (unsigned int*)((char*)d_ws + (size_t)2 * BB * HH * sizeof(float));

    hipFuncSetAttribute((const void*)lstm_main,
                        hipFuncAttributeMaxDynamicSharedMemorySize, LDS_BYTES);

    hipMemsetAsync(flags, 0, NWG * 64 * sizeof(unsigned int), stream);
    hipLaunchKernelGGL(lstm_main, dim3(NWG), dim3(BLOCK), LDS_BYTES, stream,
                       x, hs0, cs0, W_ih, W_hh, b_ih, b_hh, hbuf, flags);
    // t=783 writes hbuf[(784)&1] = hbuf[0]
    hipLaunchKernelGGL(lstm_out, dim3(BB), dim3(64), 0, stream,
                       hbuf, W_out, b_out, out);
}

// Round 4
// 4316.464 us; speedup vs baseline: 10.6041x; 10.6041x over previous
//
#include <hip/hip_runtime.h>
#include <math.h>

// LSTM: B=64, T=784, I=1, H=600.
// 200 WGs = 50 cell-groups x 4 batch-groups. 12 cells x 16 batches per WG.
// W_hh in REGISTERS (120 VGPR/lane), h exchanged via IF$ (sc0 sc1), LDS holds h only.
#define BB 64
#define TT 784
#define HH 600
#define CG 50           // cell-groups
#define SGN 4           // batch-groups
#define CPW 12          // cells per WG  -> 48 gate-rows
#define BW 16           // batches per WG
#define NWG (CG*SGN)    // 200
#define BLOCK 512       // 8 waves; wave owns 6 gate-rows; lane=(bh:2 x kh:32)
#define HB4 (BW*150)    // 2400 float4 of h per WG
#define LDS_BYTES (84*1024)   // force 1 WG/CU

__device__ __forceinline__ float dot4acc(float4 a, float4 b, float acc) {
    acc = fmaf(a.x, b.x, acc);
    acc = fmaf(a.y, b.y, acc);
    acc = fmaf(a.z, b.z, acc);
    acc = fmaf(a.w, b.w, acc);
    return acc;
}

// five pipelined cache-bypassing 16B loads (one IF$ latency)
__device__ __forceinline__ void ldg5_bypass(const float4* g0, const float4* g1,
                                            const float4* g2, const float4* g3,
                                            const float4* g4,
                                            float4& a, float4& b, float4& c,
                                            float4& d, float4& e) {
    asm volatile(
        "global_load_dwordx4 %0, %5, off sc0 sc1\n\t"
        "global_load_dwordx4 %1, %6, off sc0 sc1\n\t"
        "global_load_dwordx4 %2, %7, off sc0 sc1\n\t"
        "global_load_dwordx4 %3, %8, off sc0 sc1\n\t"
        "global_load_dwordx4 %4, %9, off sc0 sc1\n\t"
        "s_waitcnt vmcnt(0)"
        : "=&v"(a), "=&v"(b), "=&v"(c), "=&v"(d), "=&v"(e)
        : "v"(g0), "v"(g1), "v"(g2), "v"(g3), "v"(g4)
        : "memory");
}

__device__ __forceinline__ void stg_bypass(float* p, float v) {
    asm volatile("global_store_dword %0, %1, off sc0 sc1"
                 :: "v"(p), "v"(v) : "memory");
}

__device__ __forceinline__ float sigm_f(float v) {
    return 1.f / (1.f + __expf(-v));
}
__device__ __forceinline__ float tanh_f(float v) {
    return 1.f - 2.f / (__expf(2.f * v) + 1.f);
}

// fold CNT*2 partial sums down to CNT across lane-pairs (kh ^ MASK).
// After the call, slot i holds value (i + CNT*hi_bit) summed over the pair.
template<int MASK, int CNT>
__device__ __forceinline__ void fold(float* v, int kh) {
    const bool hi = (kh & MASK) != 0;
    #pragma unroll
    for (int i = 0; i < CNT; ++i) {
        float send = hi ? v[i] : v[i + CNT];
        float recv = __shfl_xor(send, MASK);
        v[i] = (hi ? v[i + CNT] : v[i]) + recv;
    }
}

extern "C" __global__ void __launch_bounds__(BLOCK, 2)
lstm_main(const float* __restrict__ x, const float* __restrict__ hs0,
          const float* __restrict__ cs0, const float* __restrict__ W_ih,
          const float* __restrict__ W_hh, const float* __restrict__ b_ih,
          const float* __restrict__ b_hh, float* __restrict__ hbuf,
          unsigned int* __restrict__ flags)
{
    extern __shared__ float lds[];
    float4* h4l  = (float4*)lds;          // [2400] = [16 b][150 f4], no pad
    float*  g_lds = lds + 4 * HB4;        // [48 rows][16 b] gate sums

    const int wg   = blockIdx.x;
    const int cg   = wg % CG;             // cell-group
    const int sg   = wg / CG;             // batch-group
    const int tid  = threadIdx.x;
    const int w    = tid >> 6;            // wave 0..7, owns rows 6w..6w+5
    const int lane = tid & 63;
    const int bh   = lane >> 5;           // batch half (0: b0-7, 1: b8-15)
    const int kh   = lane & 31;           // k-chunk id (20 floats each)
    const int khc  = (kh < 30) ? kh : 29; // clamp idle lanes to valid addrs
    const int b0   = sg * BW;

    // ---- one-time: W_hh rows 6w..6w+5, k-chunk khc*20..+19 into registers ----
    // row r (0..47) <-> (gate g = r/12, local cell c = r%12), cell = cg*12+c.
    float4 Wr[6][5];
    #pragma unroll
    for (int r = 0; r < 6; ++r) {
        const int row = 6 * w + r;
        const int g   = row / 12, c = row % 12;
        const float* wrow = W_hh + ((size_t)g * HH + cg * CPW + c) * HH + khc * 20;
        #pragma unroll
        for (int j = 0; j < 5; ++j)
            Wr[r][j] = (kh < 30) ? *(const float4*)(wrow + 4 * j)
                                 : make_float4(0.f, 0.f, 0.f, 0.f);
    }

    // ---- pointwise-lane constants (tid<192 owns (cell c=tid>>4, batch b=tid&15)) ----
    float wihv[4], biasv[4], cst = 0.f;
    const int pc = tid >> 4, pb = tid & 15;
    const int cell = cg * CPW + pc;            // valid when tid<192
    const int bglob = b0 + pb;
    if (tid < 192) {
        #pragma unroll
        for (int g = 0; g < 4; ++g) {
            const int grow = g * HH + cell;
            wihv[g]  = W_ih[grow];
            biasv[g] = b_ih[grow] + b_hh[grow];
        }
        cst = cs0[(size_t)bglob * HH + cell];
    }

    // stage indices (linear in both src and LDS): f4 idx = b*150 + col
    const int i0 = tid, i1 = tid + 512, i2 = tid + 1024, i3 = tid + 1536;
    const int i4 = (tid + 2048 < HB4) ? tid + 2048 : HB4 - 1;

    unsigned int* myflag = &flags[wg * 16];

    for (int t = 0; t < TT; ++t) {
        // x prefetch (cached, read-only)
        float xv = 0.f;
        if (tid < 192) xv = x[(size_t)bglob * TT + t];

        // ---- wait for all 50 producers of our batch-group (sleep-backoff) ----
        if (t > 0) {
            if (tid < CG) {
                const unsigned int* f = &flags[(sg * CG + tid) * 16];
                while (__hip_atomic_load(f, __ATOMIC_RELAXED,
                                         __HIP_MEMORY_SCOPE_AGENT) < (unsigned)t)
                    __builtin_amdgcn_s_sleep(1);
            }
        }
        __syncthreads();

        // ---- stage h[16][600] -> LDS via 5 pipelined IF$-bypass loads ----
        {
            const float* hsrc = (t == 0) ? hs0 : (hbuf + (size_t)(t & 1) * BB * HH);
            const float4* s4 = (const float4*)hsrc + (size_t)b0 * 150;
            float4 v0, v1, v2, v3, v4;
            ldg5_bypass(s4 + i0, s4 + i1, s4 + i2, s4 + i3, s4 + i4,
                        v0, v1, v2, v3, v4);
            h4l[i0] = v0; h4l[i1] = v1; h4l[i2] = v2; h4l[i3] = v3; h4l[i4] = v4;
        }
        __syncthreads();

        // ---- GEMV: v[r*8+bi] = sum over this lane's 20-k slice, 8 batches ----
        float v[48] = {};
        {
            const float4* hb_base = h4l + (size_t)bh * 8 * 150 + khc * 5;
            #pragma unroll
            for (int bi = 0; bi < 8; ++bi) {
                const float4* hb = hb_base + bi * 150;
                const float4 h0 = hb[0], h1 = hb[1], h2 = hb[2],
                             h3 = hb[3], hv4 = hb[4];
                #pragma unroll
                for (int r = 0; r < 6; ++r) {
                    float a = v[r * 8 + bi];
                    a = dot4acc(Wr[r][0], h0, a);
                    a = dot4acc(Wr[r][1], h1, a);
                    a = dot4acc(Wr[r][2], h2, a);
                    a = dot4acc(Wr[r][3], h3, a);
                    a = dot4acc(Wr[r][4], hv4, a);
                    v[r * 8 + bi] = a;
                }
            }
        }

        // ---- folding reduction over the 32 kh-lanes: 48 -> 24 -> 12 -> 6 -> 3 ----
        fold<16, 24>(v, kh);
        fold<8, 12>(v, kh);
        fold<4, 6>(v, kh);
        fold<2, 3>(v, kh);
        #pragma unroll
        for (int i = 0; i < 3; ++i)
            v[i] += __shfl_xor(v[i], 1);

        // ---- gather: even-kh lanes write their 3 final sums ----
        // value id = 3*(kh>>1)+s = rowl*8+bi  (rowl 0..5, bi 0..7)
        if (!(kh & 1)) {
            const int vb = 3 * (kh >> 1);
            #pragma unroll
            for (int s = 0; s < 3; ++s) {
                const int val = vb + s;
                const int rowl = val >> 3, bi = val & 7;
                g_lds[(6 * w + rowl) * 16 + bh * 8 + bi] = v[s];
            }
        }
        __syncthreads();

        // ---- pointwise LSTM cell update (192 lanes) + bypass-store h ----
        float* hdst = hbuf + (size_t)((t + 1) & 1) * BB * HH;
        if (tid < 192) {
            const float gi = g_lds[(0 * 12 + pc) * 16 + pb] + xv * wihv[0] + biasv[0];
            const float gf = g_lds[(1 * 12 + pc) * 16 + pb] + xv * wihv[1] + biasv[1];
            const float gg = g_lds[(2 * 12 + pc) * 16 + pb] + xv * wihv[2] + biasv[2];
            const float go = g_lds[(3 * 12 + pc) * 16 + pb] + xv * wihv[3] + biasv[3];
            const float cn = sigm_f(gf) * cst + sigm_f(gi) * tanh_f(gg);
            cst = cn;
            stg_bypass(&hdst[(size_t)bglob * HH + cell], sigm_f(go) * tanh_f(cn));
        }
        __syncthreads();   // per-wave vmcnt(0) drain before barrier: stores in IF$
        if (tid == 0)
            __hip_atomic_store(myflag, (unsigned)(t + 1), __ATOMIC_RELAXED,
                               __HIP_MEMORY_SCOPE_AGENT);
    }
}

// final projection: out[b,o] = h_T[b,:] @ W_out[o,:] + b_out[o]
extern "C" __global__ void lstm_out(const float* __restrict__ hbuf0,
                                    const float* __restrict__ W_out,
                                    const float* __restrict__ b_out,
                                    float* __restrict__ out)
{
    int b = blockIdx.x;
    int lane = threadIdx.x;
    float acc[10] = {};
    for (int k = lane; k < HH; k += 64) {
        float hv = hbuf0[(size_t)b * HH + k];
        #pragma unroll
        for (int o = 0; o < 10; ++o)
            acc[o] += hv * W_out[(size_t)o * HH + k];
    }
    #pragma unroll
    for (int o = 0; o < 10; ++o) {
        float v = acc[o];
        for (int off = 32; off > 0; off >>= 1) v += __shfl_down(v, off);
        if (lane == 0) out[b * 10 + o] = v + b_out[o];
    }
}

extern "C" void kernel_launch(void* const* d_in, const int* in_sizes, int n_in,
                              void* d_out, int out_size, void* d_ws, size_t ws_size,
                              hipStream_t stream)
{
    const float* x     = (const float*)d_in[0];
    const float* hs0   = (const float*)d_in[1];
    const float* cs0   = (const float*)d_in[2];
    const float* W_ih  = (const float*)d_in[3];
    const float* W_hh  = (const float*)d_in[4];
    const float* b_ih  = (const float*)d_in[5];
    const float* b_hh  = (const float*)d_in[6];
    const float* W_out = (const float*)d_in[7];
    const float* b_out = (const float*)d_in[8];
    float* out = (float*)d_out;

    // workspace: hbuf[2][64][600] f32, then flags[200] spaced 64 B
    float* hbuf = (float*)d_ws;
    unsigned int* flags = (unsigned int*)((char*)d_ws + (size_t)2 * BB * HH * sizeof(float));

    hipFuncSetAttribute((const void*)lstm_main,
                        hipFuncAttributeMaxDynamicSharedMemorySize, LDS_BYTES);

    hipMemsetAsync(flags, 0, NWG * 16 * sizeof(unsigned int), stream);
    hipLaunchKernelGGL(lstm_main, dim3(NWG), dim3(BLOCK), LDS_BYTES, stream,
                       x, hs0, cs0, W_ih, W_hh, b_ih, b_hh, hbuf, flags);
    // t=783 writes hbuf[(784)&1] = hbuf[0]
    hipLaunchKernelGGL(lstm_out, dim3(BB), dim3(64), 0, stream,
                       hbuf, W_out, b_out, out);
}